// Round 10
// baseline (520.283 us; speedup 1.0000x reference)
//
#include <hip/hip_runtime.h>
#include <hip/hip_fp16.h>

#define NN 100000
#define NSB 256            // dst windows (one ownership block each)
#define WPS2 391           // dst nodes per window (ceil(NN/NSB))
#define CAP2 8192          // edge capacity per window (mean 6256)
#define EPB 16             // edges per thread in split

typedef _Float16 f16;
typedef _Float16 f16x8 __attribute__((ext_vector_type(8)));
typedef float f32x4 __attribute__((ext_vector_type(4)));

__device__ __forceinline__ int eload(const void* e, long i, int is64) {
  if (is64) return (int)((const long long*)e)[i];
  return ((const int*)e)[i];
}

// detect int32/int64 (odd words zero => int64) + init bcur2
__global__ __launch_bounds__(1024) void k_detect(const unsigned* __restrict__ e,
                                                 int* __restrict__ flag,
                                                 int* __restrict__ bcur2) {
  __shared__ unsigned red[1024];
  int t = threadIdx.x;
  if (t < NSB) bcur2[t] = t * CAP2;
  unsigned acc = e[1 + 2 * t] | e[1 + 2 * t + 2048];
  red[t] = acc;
  __syncthreads();
  for (int off = 512; off > 0; off >>= 1) {
    if (t < off) red[t] |= red[t + off];
    __syncthreads();
  }
  if (t == 0) *flag = (red[0] == 0) ? 1 : 0;  // 1 => int64
}

// both weights: Wt[n][k] fp16 from W[k][n] fp32
__global__ void k_wprep(const float* __restrict__ W1, const float* __restrict__ W2,
                        f16* __restrict__ Wt1, f16* __restrict__ Wt2) {
  int idx = blockIdx.x * 256 + threadIdx.x;
  if (idx < 128 * 128) {
    int k = idx / 128, n = idx % 128;
    Wt1[n * 128 + k] = (f16)W1[idx];
  } else {
    int i2 = idx - 128 * 128;
    if (i2 < 128 * 64) {
      int k = i2 / 64, n = i2 % 64;
      Wt2[n * 128 + k] = (f16)W2[i2];
    }
  }
}

// ---------------------------------------------------------------------------
// 256-way multi-split by dst window (SoA srcb/dstb, contiguous runs).
// ---------------------------------------------------------------------------
__global__ __launch_bounds__(256) void k_split(const void* __restrict__ e,
                                               const int* __restrict__ flag,
                                               int E, int* __restrict__ bcur2,
                                               int* __restrict__ srcb,
                                               int* __restrict__ dstb) {
  __shared__ int hist[NSB];
  const int tid = threadIdx.x;
  const long b0 = (long)blockIdx.x * (256 * EPB);
  const int is64 = *flag;
  hist[tid] = 0;
  __syncthreads();

  int sv[EPB], dv[EPB];
#pragma unroll
  for (int j = 0; j < EPB; ++j) {
    long idx = b0 + j * 256 + tid;
    int s = 0, d = -1;
    if (idx < E) {
      s = eload(e, idx, is64);
      d = eload(e, (long)E + idx, is64);
    }
    sv[j] = s; dv[j] = d;
    if (d >= 0) atomicAdd(&hist[(unsigned)d / WPS2], 1);
  }
  __syncthreads();
  {
    int c = hist[tid];
    int base = (c > 0) ? atomicAdd(&bcur2[tid], c) : 0;
    __syncthreads();
    hist[tid] = base;
  }
  __syncthreads();
#pragma unroll
  for (int j = 0; j < EPB; ++j) {
    int d = dv[j];
    if (d < 0) continue;
    int pos = atomicAdd(&hist[(unsigned)d / WPS2], 1);
    srcb[pos] = sv[j];
    dstb[pos] = d;
  }
}

// scan of 256 window totals -> wbase; rowptr[NN]=E
__global__ __launch_bounds__(256) void k_wscan(const int* __restrict__ bcur2,
                                               int* __restrict__ wbase,
                                               int* __restrict__ rowptr, int E) {
  __shared__ int sm[NSB];
  int t = threadIdx.x;
  int c = bcur2[t] - t * CAP2;
  sm[t] = c;
  __syncthreads();
  for (int off = 1; off < NSB; off <<= 1) {
    int a = (t >= off) ? sm[t - off] : 0;
    __syncthreads();
    sm[t] += a;
    __syncthreads();
  }
  wbase[t] = sm[t] - c;
  if (t == 0) rowptr[NN] = E;
}

// ---------------------------------------------------------------------------
// Fused per-window build: LDS hist -> LDS scan -> rowptr+dinv -> csr replay.
// ---------------------------------------------------------------------------
__global__ __launch_bounds__(256) void k_build(const int* __restrict__ dstb,
                                               const int* __restrict__ srcb,
                                               const int* __restrict__ bcur2,
                                               const int* __restrict__ wbase,
                                               int* __restrict__ rowptr,
                                               float* __restrict__ dinv,
                                               int* __restrict__ csr) {
  __shared__ int lc[512];
  __shared__ int cur[512];
  const int tid = threadIdx.x;
  const int b = blockIdx.x;
  const int nlo = b * WPS2;
  const int nhi = (nlo + WPS2 < NN) ? nlo + WPS2 : NN;
  const int nw = nhi - nlo;
  lc[tid] = 0; lc[tid + 256] = 0;
  __syncthreads();
  const int cnt = bcur2[b] - b * CAP2;
  const long s0 = (long)b * CAP2;
  for (int i = tid; i < cnt; i += 256)
    atomicAdd(&lc[dstb[s0 + i] - nlo], 1);
  __syncthreads();
  for (int off = 1; off < 512; off <<= 1) {
    int a0 = (tid >= off) ? lc[tid - off] : 0;
    int a1 = (tid + 256 >= off) ? lc[tid + 256 - off] : 0;
    __syncthreads();
    lc[tid] += a0; lc[tid + 256] += a1;
    __syncthreads();
  }
  const int wb = wbase[b];
#pragma unroll
  for (int h = 0; h < 2; ++h) {
    int j = tid + h * 256;
    if (j < nw) {
      int inc = lc[j];
      int c = inc - (j > 0 ? lc[j - 1] : 0);
      int ex = wb + inc - c;
      rowptr[nlo + j] = ex;
      dinv[nlo + j] = rsqrtf((float)c + 1.0f);  // +1 self-loop
      cur[j] = ex;
    }
  }
  __syncthreads();
  for (int i = tid; i < cnt; i += 256) {
    int d = dstb[s0 + i];
    int pos = atomicAdd(&cur[d - nlo], 1);
    csr[pos] = srcb[s0 + i];
  }
}

// ---------------------------------------------------------------------------
// MFMA GEMM: Y[row] = ((relu?)X[row] @ W) * dinv[row], fp16 out.
// ---------------------------------------------------------------------------
template <int COUT, bool RELU, typename TIN>
__global__ __launch_bounds__(256) void gemm_mfma(const TIN* __restrict__ X,
                                                 const f16* __restrict__ Wt,
                                                 const float* __restrict__ dinv,
                                                 f16* __restrict__ Y) {
  constexpr int NF = COUT / 16;
  __shared__ f16 Al[128 * 128];
  __shared__ f16 Bl[COUT * 128];
  const int tid = threadIdx.x;
  const long row0 = (long)blockIdx.x * 128;

  for (int c = tid; c < COUT * 16; c += 256) {
    int n = c >> 4, g = c & 15;
    f16x8 v = *(const f16x8*)&Wt[n * 128 + g * 8];
    *(f16x8*)((char*)Bl + n * 256 + ((g * 16) ^ ((n & 7) << 4))) = v;
  }
  for (int c = tid; c < 2048; c += 256) {
    int r = c >> 4, g = c & 15;
    long grow = row0 + r;
    f16x8 v;
    if (grow < NN) {
      if constexpr (sizeof(TIN) == 4) {
        const float4* p = (const float4*)&X[grow * 128 + g * 8];
        float4 p0 = p[0], p1 = p[1];
        float f[8] = {p0.x, p0.y, p0.z, p0.w, p1.x, p1.y, p1.z, p1.w};
#pragma unroll
        for (int j = 0; j < 8; ++j) {
          float t = RELU ? fmaxf(f[j], 0.f) : f[j];
          v[j] = (f16)t;
        }
      } else {
        v = *(const f16x8*)&X[grow * 128 + g * 8];
        if (RELU) {
#pragma unroll
          for (int j = 0; j < 8; ++j) v[j] = v[j] > (f16)0 ? v[j] : (f16)0;
        }
      }
    } else {
#pragma unroll
      for (int j = 0; j < 8; ++j) v[j] = (f16)0;
    }
    *(f16x8*)((char*)Al + r * 256 + ((g * 16) ^ ((r & 7) << 4))) = v;
  }
  __syncthreads();

  const int l = tid & 63, w = tid >> 6;
  const int lm = l & 15, lg = l >> 4;
  const int r0 = w * 32 + lm, r1 = r0 + 16;

  f32x4 acc0[NF], acc1[NF];
#pragma unroll
  for (int nf = 0; nf < NF; ++nf) { acc0[nf] = (f32x4)(0.f); acc1[nf] = (f32x4)(0.f); }

#pragma unroll
  for (int kk = 0; kk < 4; ++kk) {
    const int kb = kk * 64 + lg * 16;
    f16x8 a0 = *(const f16x8*)((const char*)Al + r0 * 256 + (kb ^ ((r0 & 7) << 4)));
    f16x8 a1 = *(const f16x8*)((const char*)Al + r1 * 256 + (kb ^ ((r1 & 7) << 4)));
#pragma unroll
    for (int nf = 0; nf < NF; ++nf) {
      int n = nf * 16 + lm;
      f16x8 b = *(const f16x8*)((const char*)Bl + n * 256 + (kb ^ ((n & 7) << 4)));
      acc0[nf] = __builtin_amdgcn_mfma_f32_16x16x32_f16(a0, b, acc0[nf], 0, 0, 0);
      acc1[nf] = __builtin_amdgcn_mfma_f32_16x16x32_f16(a1, b, acc1[nf], 0, 0, 0);
    }
  }

#pragma unroll
  for (int reg = 0; reg < 4; ++reg) {
    long gr0 = row0 + w * 32 + lg * 4 + reg;
    long gr1 = gr0 + 16;
    float d0 = (gr0 < NN) ? dinv[gr0] : 0.f;
    float d1 = (gr1 < NN) ? dinv[gr1] : 0.f;
#pragma unroll
    for (int nf = 0; nf < NF; ++nf) {
      if (gr0 < NN) Y[gr0 * COUT + nf * 16 + lm] = (f16)(acc0[nf][reg] * d0);
      if (gr1 < NN) Y[gr1 * COUT + nf * 16 + lm] = (f16)(acc1[nf][reg] * d1);
    }
  }
}

// ---------------------------------------------------------------------------
// Channel-sliced gather agg: slice = blockIdx&7 -> (round-robin) one XCD per
// slice; that XCD's gather working set is hn[:, slice-channels] (3.2MB/1.6MB)
// -> L2-resident, ~16x reuse per line. 8-deep load pipeline per row.
// out[d, sc] = dinv[d]*(hn[d,sc] + sum_{s in N(d)} hn[s,sc]) + bias[sc].
// SCH: channels per slice (16 for C=128 -> TP=2; 8 for C=64 -> TP=1).
// ---------------------------------------------------------------------------
template <int C, int SCH, typename TOUT>
__global__ __launch_bounds__(256) void k_aggs(const f16* __restrict__ hn,
                                              const int* __restrict__ rowptr,
                                              const int* __restrict__ csr,
                                              const float* __restrict__ dinv,
                                              const float* __restrict__ bias,
                                              TOUT* __restrict__ out) {
  constexpr int TP = SCH / 8;          // threads per row (16B = 8 halves each)
  constexpr int RPB = 256 / TP;        // rows per block
  const int slice = blockIdx.x & 7;
  const int tid = threadIdx.x;
  const long d = (long)(blockIdx.x >> 3) * RPB + tid / TP;
  if (d >= NN) return;
  const int c8 = slice * SCH + (tid % TP) * 8;

  float acc[8];
  {
    f16x8 v = *(const f16x8*)&hn[d * C + c8];   // self-loop message
#pragma unroll
    for (int j = 0; j < 8; ++j) acc[j] = (float)v[j];
  }
  int e = rowptr[d];
  const int end = rowptr[d + 1];

  for (; e + 8 <= end; e += 8) {
    int s[8];
#pragma unroll
    for (int u = 0; u < 8; ++u) s[u] = csr[e + u];
    f16x8 r[8];
#pragma unroll
    for (int u = 0; u < 8; ++u) r[u] = *(const f16x8*)&hn[(long)s[u] * C + c8];
#pragma unroll
    for (int u = 0; u < 8; ++u)
#pragma unroll
      for (int j = 0; j < 8; ++j) acc[j] += (float)r[u][j];
  }
  if (e + 4 <= end) {
    int s[4];
#pragma unroll
    for (int u = 0; u < 4; ++u) s[u] = csr[e + u];
    f16x8 r[4];
#pragma unroll
    for (int u = 0; u < 4; ++u) r[u] = *(const f16x8*)&hn[(long)s[u] * C + c8];
#pragma unroll
    for (int u = 0; u < 4; ++u)
#pragma unroll
      for (int j = 0; j < 8; ++j) acc[j] += (float)r[u][j];
    e += 4;
  }
  for (; e < end; ++e) {
    f16x8 r0 = *(const f16x8*)&hn[(long)csr[e] * C + c8];
#pragma unroll
    for (int j = 0; j < 8; ++j) acc[j] += (float)r0[j];
  }

  float dd = dinv[d];
  float4 bv0 = *(const float4*)&bias[c8];
  float4 bv1 = *(const float4*)&bias[c8 + 4];
  const float bb[8] = {bv0.x, bv0.y, bv0.z, bv0.w, bv1.x, bv1.y, bv1.z, bv1.w};
  float o[8];
#pragma unroll
  for (int j = 0; j < 8; ++j) o[j] = acc[j] * dd + bb[j];

  if constexpr (sizeof(TOUT) == 2) {
    f16x8 hv;
#pragma unroll
    for (int j = 0; j < 8; ++j) hv[j] = (f16)o[j];
    *(f16x8*)&out[d * C + c8] = hv;
  } else {
    *(float4*)&out[d * C + c8]     = make_float4(o[0], o[1], o[2], o[3]);
    *(float4*)&out[d * C + c8 + 4] = make_float4(o[4], o[5], o[6], o[7]);
  }
}

extern "C" void kernel_launch(void* const* d_in, const int* in_sizes, int n_in,
                              void* d_out, int out_size, void* d_ws, size_t ws_size,
                              hipStream_t stream) {
  const float* x  = (const float*)d_in[0];
  const void*  ep = d_in[1];
  const float* W1 = (const float*)d_in[2];
  const float* b1 = (const float*)d_in[3];
  const float* W2 = (const float*)d_in[4];
  const float* b2 = (const float*)d_in[5];
  float* out = (float*)d_out;
  const int E = in_sizes[1] / 2;

  // workspace layout (int-element offsets)
  float*  wsf    = (float*)d_ws;
  int*    wsi    = (int*)d_ws;
  int*    flag   = wsi;                        // [0]
  int*    bcur2  = wsi + 64;                   // 256
  int*    wbase  = wsi + 320;                  // 256
  float*  dinv   = wsf + 576;                  // 100000
  int*    rowptr = wsi + 100576;               // 100001
  f16*    Wt1    = (f16*)(wsi + 200640);       // 16384 halves
  f16*    Wt2    = (f16*)(wsi + 208832);       // 8192 halves
  int*    csr    = wsi + 212992;               // 1600000
  int*    srcb   = wsi + 1812992;              // 2097152
  int*    dstb   = wsi + 3910144;              // 2097152
  f16*    hn1    = (f16*)(wsi + 6007296);      // 12.8M halves (6.4M ints)
  f16*    a1     = (f16*)(wsi + 12407296);     // 12.8M halves (6.4M ints)
  f16*    hn2    = hn1;                        // hn1 dead once a1 built

  const int SB = (E + 256 * EPB - 1) / (256 * EPB);  // 391
  const int GB = (NN + 127) / 128;                   // 782

  k_detect<<<1, 1024, 0, stream>>>((const unsigned*)ep, flag, bcur2);
  k_wprep<<<96, 256, 0, stream>>>(W1, W2, Wt1, Wt2);
  k_split<<<SB, 256, 0, stream>>>(ep, flag, E, bcur2, srcb, dstb);
  k_wscan<<<1, 256, 0, stream>>>(bcur2, wbase, rowptr, E);
  k_build<<<NSB, 256, 0, stream>>>(dstb, srcb, bcur2, wbase, rowptr, dinv, csr);

  // layer 1: hn1 = (x @ W1) * dinv ; a1 = dinv*(self + gather) + b1
  gemm_mfma<128, false, float><<<GB, 256, 0, stream>>>(x, Wt1, dinv, hn1);
  {
    const int AB = 8 * ((NN + 127) / 128);  // 8 slices x 782
    k_aggs<128, 16, f16><<<AB, 256, 0, stream>>>(hn1, rowptr, csr, dinv, b1, a1);
  }

  // layer 2: hn2 = (relu(a1) @ W2) * dinv ; out = dinv*(self + gather) + b2
  gemm_mfma<64, true, f16><<<GB, 256, 0, stream>>>(a1, Wt2, dinv, hn2);
  {
    const int AB = 8 * ((NN + 255) / 256);  // 8 slices x 391
    k_aggs<64, 8, float><<<AB, 256, 0, stream>>>(hn2, rowptr, csr, dinv, b2, out);
  }
}

// Round 12
// 226.611 us; speedup vs baseline: 2.2959x; 2.2959x over previous
//
#include <hip/hip_runtime.h>
#include <hip/hip_fp16.h>

#define NN 100000
#define NSB 256            // dst windows (one ownership block each)
#define WPS2 391           // dst nodes per window (ceil(NN/NSB))
#define CAP2 8192          // edge capacity per window (mean 6256)
#define EPB 16             // edges per thread in split

typedef _Float16 f16;
typedef _Float16 f16x8 __attribute__((ext_vector_type(8)));
typedef float f32x4 __attribute__((ext_vector_type(4)));

__device__ __forceinline__ int eload(const void* e, long i, int is64) {
  if (is64) return (int)((const long long*)e)[i];
  return ((const int*)e)[i];
}

// ---------------------------------------------------------------------------
// Block 0: dtype sniff (odd words zero => int64) + padded-cursor init.
// Blocks 1..24: weight prep Wt[n][k] fp16 from W[k][n] fp32 (both layers).
// bcur2 is PADDED: counter w lives at bcur2[w*16] (own 64B line -> no L2
// atomic line contention from the run-allocation atomics in k_split).
// ---------------------------------------------------------------------------
__global__ __launch_bounds__(1024) void k_prep(const unsigned* __restrict__ e,
                                               int* __restrict__ flag,
                                               int* __restrict__ bcur2,
                                               const float* __restrict__ W1,
                                               const float* __restrict__ W2,
                                               f16* __restrict__ Wt1,
                                               f16* __restrict__ Wt2) {
  const int t = threadIdx.x;
  if (blockIdx.x == 0) {
    __shared__ unsigned red[1024];
    if (t < NSB) bcur2[t * 16] = t * CAP2;
    unsigned acc = e[1 + 2 * t] | e[1 + 2 * t + 2048];
    red[t] = acc;
    __syncthreads();
    for (int off = 512; off > 0; off >>= 1) {
      if (t < off) red[t] |= red[t + off];
      __syncthreads();
    }
    if (t == 0) *flag = (red[0] == 0) ? 1 : 0;  // 1 => int64
  } else {
    int idx = (blockIdx.x - 1) * 1024 + t;
    if (idx < 128 * 128) {
      int k = idx / 128, n = idx % 128;
      Wt1[n * 128 + k] = (f16)W1[idx];
    } else {
      int i2 = idx - 128 * 128;
      if (i2 < 128 * 64) {
        int k = i2 / 64, n = i2 % 64;
        Wt2[n * 128 + k] = (f16)W2[i2];
      }
    }
  }
}

// ---------------------------------------------------------------------------
// 256-way multi-split by dst window; output PACKED: (dloc<<17)|src (one int
// per edge; src<2^17, dloc<2^9). Contiguous runs per window.
// ---------------------------------------------------------------------------
__global__ __launch_bounds__(256) void k_split(const void* __restrict__ e,
                                               const int* __restrict__ flag,
                                               int E, int* __restrict__ bcur2,
                                               int* __restrict__ pk) {
  __shared__ int hist[NSB];
  const int tid = threadIdx.x;
  const long b0 = (long)blockIdx.x * (256 * EPB);
  const int is64 = *flag;
  hist[tid] = 0;
  __syncthreads();

  int sv[EPB], dv[EPB];
#pragma unroll
  for (int j = 0; j < EPB; ++j) {
    long idx = b0 + j * 256 + tid;
    int s = 0, d = -1;
    if (idx < E) {
      s = eload(e, idx, is64);
      d = eload(e, (long)E + idx, is64);
    }
    sv[j] = s; dv[j] = d;
    if (d >= 0) atomicAdd(&hist[(unsigned)d / WPS2], 1);
  }
  __syncthreads();
  {
    int c = hist[tid];
    int base = (c > 0) ? atomicAdd(&bcur2[tid * 16], c) : 0;
    __syncthreads();
    hist[tid] = base;
  }
  __syncthreads();
#pragma unroll
  for (int j = 0; j < EPB; ++j) {
    int d = dv[j];
    if (d < 0) continue;
    int w = (unsigned)d / WPS2;
    int dloc = d - w * WPS2;
    int pos = atomicAdd(&hist[w], 1);
    pk[pos] = (dloc << 17) | sv[j];
  }
}

// scan of 256 window totals -> wbase; rowptr[NN]=E
__global__ __launch_bounds__(256) void k_wscan(const int* __restrict__ bcur2,
                                               int* __restrict__ wbase,
                                               int* __restrict__ rowptr, int E) {
  __shared__ int sm[NSB];
  int t = threadIdx.x;
  int c = bcur2[t * 16] - t * CAP2;
  sm[t] = c;
  __syncthreads();
  for (int off = 1; off < NSB; off <<= 1) {
    int a = (t >= off) ? sm[t - off] : 0;
    __syncthreads();
    sm[t] += a;
    __syncthreads();
  }
  wbase[t] = sm[t] - c;
  if (t == 0) rowptr[NN] = E;
}

// ---------------------------------------------------------------------------
// Fused per-window build: LDS hist -> LDS scan -> rowptr+dinv -> csr replay.
// Reads packed run (one int/edge).
// ---------------------------------------------------------------------------
__global__ __launch_bounds__(256) void k_build(const int* __restrict__ pk,
                                               const int* __restrict__ bcur2,
                                               const int* __restrict__ wbase,
                                               int* __restrict__ rowptr,
                                               float* __restrict__ dinv,
                                               int* __restrict__ csr) {
  __shared__ int lc[512];
  __shared__ int cur[512];
  const int tid = threadIdx.x;
  const int b = blockIdx.x;
  const int nlo = b * WPS2;
  const int nhi = (nlo + WPS2 < NN) ? nlo + WPS2 : NN;
  const int nw = nhi - nlo;
  lc[tid] = 0; lc[tid + 256] = 0;
  __syncthreads();
  const int cnt = bcur2[b * 16] - b * CAP2;
  const long s0 = (long)b * CAP2;
  for (int i = tid; i < cnt; i += 256)
    atomicAdd(&lc[(unsigned)pk[s0 + i] >> 17], 1);
  __syncthreads();
  for (int off = 1; off < 512; off <<= 1) {
    int a0 = (tid >= off) ? lc[tid - off] : 0;
    int a1 = (tid + 256 >= off) ? lc[tid + 256 - off] : 0;
    __syncthreads();
    lc[tid] += a0; lc[tid + 256] += a1;
    __syncthreads();
  }
  const int wb = wbase[b];
#pragma unroll
  for (int h = 0; h < 2; ++h) {
    int j = tid + h * 256;
    if (j < nw) {
      int inc = lc[j];
      int c = inc - (j > 0 ? lc[j - 1] : 0);
      int ex = wb + inc - c;
      rowptr[nlo + j] = ex;
      dinv[nlo + j] = rsqrtf((float)c + 1.0f);  // +1 self-loop
      cur[j] = ex;
    }
  }
  __syncthreads();
  for (int i = tid; i < cnt; i += 256) {
    int p = pk[s0 + i];
    int pos = atomicAdd(&cur[(unsigned)p >> 17], 1);
    csr[pos] = p & 0x1FFFF;
  }
}

// ---------------------------------------------------------------------------
// MFMA GEMM: Y[row] = ((relu?)X[row] @ W) * dinv[row], fp16 out.
// ---------------------------------------------------------------------------
template <int COUT, bool RELU, typename TIN>
__global__ __launch_bounds__(256) void gemm_mfma(const TIN* __restrict__ X,
                                                 const f16* __restrict__ Wt,
                                                 const float* __restrict__ dinv,
                                                 f16* __restrict__ Y) {
  constexpr int NF = COUT / 16;
  __shared__ f16 Al[128 * 128];
  __shared__ f16 Bl[COUT * 128];
  const int tid = threadIdx.x;
  const long row0 = (long)blockIdx.x * 128;

  for (int c = tid; c < COUT * 16; c += 256) {
    int n = c >> 4, g = c & 15;
    f16x8 v = *(const f16x8*)&Wt[n * 128 + g * 8];
    *(f16x8*)((char*)Bl + n * 256 + ((g * 16) ^ ((n & 7) << 4))) = v;
  }
  for (int c = tid; c < 2048; c += 256) {
    int r = c >> 4, g = c & 15;
    long grow = row0 + r;
    f16x8 v;
    if (grow < NN) {
      if constexpr (sizeof(TIN) == 4) {
        const float4* p = (const float4*)&X[grow * 128 + g * 8];
        float4 p0 = p[0], p1 = p[1];
        float f[8] = {p0.x, p0.y, p0.z, p0.w, p1.x, p1.y, p1.z, p1.w};
#pragma unroll
        for (int j = 0; j < 8; ++j) {
          float t = RELU ? fmaxf(f[j], 0.f) : f[j];
          v[j] = (f16)t;
        }
      } else {
        v = *(const f16x8*)&X[grow * 128 + g * 8];
        if (RELU) {
#pragma unroll
          for (int j = 0; j < 8; ++j) v[j] = v[j] > (f16)0 ? v[j] : (f16)0;
        }
      }
    } else {
#pragma unroll
      for (int j = 0; j < 8; ++j) v[j] = (f16)0;
    }
    *(f16x8*)((char*)Al + r * 256 + ((g * 16) ^ ((r & 7) << 4))) = v;
  }
  __syncthreads();

  const int l = tid & 63, w = tid >> 6;
  const int lm = l & 15, lg = l >> 4;
  const int r0 = w * 32 + lm, r1 = r0 + 16;

  f32x4 acc0[NF], acc1[NF];
#pragma unroll
  for (int nf = 0; nf < NF; ++nf) { acc0[nf] = (f32x4)(0.f); acc1[nf] = (f32x4)(0.f); }

#pragma unroll
  for (int kk = 0; kk < 4; ++kk) {
    const int kb = kk * 64 + lg * 16;
    f16x8 a0 = *(const f16x8*)((const char*)Al + r0 * 256 + (kb ^ ((r0 & 7) << 4)));
    f16x8 a1 = *(const f16x8*)((const char*)Al + r1 * 256 + (kb ^ ((r1 & 7) << 4)));
#pragma unroll
    for (int nf = 0; nf < NF; ++nf) {
      int n = nf * 16 + lm;
      f16x8 b = *(const f16x8*)((const char*)Bl + n * 256 + (kb ^ ((n & 7) << 4)));
      acc0[nf] = __builtin_amdgcn_mfma_f32_16x16x32_f16(a0, b, acc0[nf], 0, 0, 0);
      acc1[nf] = __builtin_amdgcn_mfma_f32_16x16x32_f16(a1, b, acc1[nf], 0, 0, 0);
    }
  }

#pragma unroll
  for (int reg = 0; reg < 4; ++reg) {
    long gr0 = row0 + w * 32 + lg * 4 + reg;
    long gr1 = gr0 + 16;
    float d0 = (gr0 < NN) ? dinv[gr0] : 0.f;
    float d1 = (gr1 < NN) ? dinv[gr1] : 0.f;
#pragma unroll
    for (int nf = 0; nf < NF; ++nf) {
      if (gr0 < NN) Y[gr0 * COUT + nf * 16 + lm] = (f16)(acc0[nf][reg] * d0);
      if (gr1 < NN) Y[gr1 * COUT + nf * 16 + lm] = (f16)(acc1[nf][reg] * d1);
    }
  }
}

// ---------------------------------------------------------------------------
// Gather agg, 8-deep pipeline, 1 row per TP-thread group (R9 structure —
// empirically at the random-row fabric ceiling). csr loads nontemporal
// (stream-once) so they don't evict hn rows from L2.
// ---------------------------------------------------------------------------
__device__ __forceinline__ void acc8f(float* acc, const __half* p) {
  float4 raw = *(const float4*)p;
  const __half2* h = (const __half2*)&raw;
#pragma unroll
  for (int q = 0; q < 4; ++q) {
    float2 f = __half22float2(h[q]);
    acc[2 * q] += f.x; acc[2 * q + 1] += f.y;
  }
}

template <int C, typename TOUT>
__global__ __launch_bounds__(256) void k_agg8(const __half* __restrict__ hn,
                                              const int* __restrict__ rowptr,
                                              const int* __restrict__ csr,
                                              const float* __restrict__ dinv,
                                              const float* __restrict__ bias,
                                              TOUT* __restrict__ out) {
  constexpr int TP = C / 8;
  long t = (long)blockIdx.x * 256 + threadIdx.x;
  int d = (int)(t / TP);
  if (d >= NN) return;
  int c8 = (int)(t % TP) * 8;

  float acc[8] = {0, 0, 0, 0, 0, 0, 0, 0};
  acc8f(acc, &hn[(long)d * C + c8]);  // self-loop message
  int e = rowptr[d];
  const int end = rowptr[d + 1];

  for (; e + 8 <= end; e += 8) {
    int s[8];
#pragma unroll
    for (int u = 0; u < 8; ++u) s[u] = __builtin_nontemporal_load(csr + e + u);
    float4 r[8];
#pragma unroll
    for (int u = 0; u < 8; ++u) r[u] = *(const float4*)&hn[(long)s[u] * C + c8];
#pragma unroll
    for (int u = 0; u < 8; ++u) {
      const __half2* h = (const __half2*)&r[u];
#pragma unroll
      for (int q = 0; q < 4; ++q) {
        float2 f = __half22float2(h[q]);
        acc[2 * q] += f.x; acc[2 * q + 1] += f.y;
      }
    }
  }
  if (e + 4 <= end) {
    int s[4];
#pragma unroll
    for (int u = 0; u < 4; ++u) s[u] = __builtin_nontemporal_load(csr + e + u);
    float4 r[4];
#pragma unroll
    for (int u = 0; u < 4; ++u) r[u] = *(const float4*)&hn[(long)s[u] * C + c8];
#pragma unroll
    for (int u = 0; u < 4; ++u) {
      const __half2* h = (const __half2*)&r[u];
#pragma unroll
      for (int q = 0; q < 4; ++q) {
        float2 f = __half22float2(h[q]);
        acc[2 * q] += f.x; acc[2 * q + 1] += f.y;
      }
    }
    e += 4;
  }
  for (; e < end; ++e) acc8f(acc, &hn[(long)__builtin_nontemporal_load(csr + e) * C + c8]);

  float dd = dinv[d];
  float4 bv0 = *(const float4*)&bias[c8];
  float4 bv1 = *(const float4*)&bias[c8 + 4];
  float o[8];
  o[0] = acc[0] * dd + bv0.x; o[1] = acc[1] * dd + bv0.y;
  o[2] = acc[2] * dd + bv0.z; o[3] = acc[3] * dd + bv0.w;
  o[4] = acc[4] * dd + bv1.x; o[5] = acc[5] * dd + bv1.y;
  o[6] = acc[6] * dd + bv1.z; o[7] = acc[7] * dd + bv1.w;

  if constexpr (sizeof(TOUT) == 2) {
    __half2 hp[4];
    hp[0] = __floats2half2_rn(o[0], o[1]);
    hp[1] = __floats2half2_rn(o[2], o[3]);
    hp[2] = __floats2half2_rn(o[4], o[5]);
    hp[3] = __floats2half2_rn(o[6], o[7]);
    *(float4*)&out[(long)d * C + c8] = *(float4*)hp;
  } else {
    // final fp32 output, never re-read -> nontemporal (ext-vector type: OK)
    f32x4 v0 = {o[0], o[1], o[2], o[3]};
    f32x4 v1 = {o[4], o[5], o[6], o[7]};
    __builtin_nontemporal_store(v0, (f32x4*)&out[(long)d * C + c8]);
    __builtin_nontemporal_store(v1, (f32x4*)&out[(long)d * C + c8 + 4]);
  }
}

extern "C" void kernel_launch(void* const* d_in, const int* in_sizes, int n_in,
                              void* d_out, int out_size, void* d_ws, size_t ws_size,
                              hipStream_t stream) {
  const float* x  = (const float*)d_in[0];
  const void*  ep = d_in[1];
  const float* W1 = (const float*)d_in[2];
  const float* b1 = (const float*)d_in[3];
  const float* W2 = (const float*)d_in[4];
  const float* b2 = (const float*)d_in[5];
  float* out = (float*)d_out;
  const int E = in_sizes[1] / 2;

  // workspace layout (int-element offsets)
  float*  wsf    = (float*)d_ws;
  int*    wsi    = (int*)d_ws;
  int*    flag   = wsi;                        // [0]
  int*    bcur2  = wsi + 64;                   // 256*16 padded (4096)
  int*    wbase  = wsi + 4224;                 // 256
  float*  dinv   = wsf + 4480;                 // 100000
  int*    rowptr = wsi + 104480;               // 100001
  f16*    Wt1    = (f16*)(wsi + 204496);       // 16384 halves (8192 ints)
  f16*    Wt2    = (f16*)(wsi + 212688);       // 8192 halves (4096 ints)
  int*    csr    = wsi + 216784;               // 1600000
  int*    pk     = wsi + 1816784;              // 256*CAP2 = 2097152
  f16*    hn1    = (f16*)(wsi + 3913936);      // 12.8M halves (6.4M ints)
  f16*    a1     = (f16*)(wsi + 10313936);     // 12.8M halves
  f16*    hn2    = hn1;                        // hn1 dead once a1 built

  const int SB = (E + 256 * EPB - 1) / (256 * EPB);  // 391
  const int GB = (NN + 127) / 128;                   // 782

  k_prep<<<25, 1024, 0, stream>>>((const unsigned*)ep, flag, bcur2, W1, W2, Wt1, Wt2);
  k_split<<<SB, 256, 0, stream>>>(ep, flag, E, bcur2, pk);
  k_wscan<<<1, 256, 0, stream>>>(bcur2, wbase, rowptr, E);
  k_build<<<NSB, 256, 0, stream>>>(pk, bcur2, wbase, rowptr, dinv, csr);

  // layer 1: hn1 = (x @ W1) * dinv ; a1 = dinv*(self + gather) + b1
  gemm_mfma<128, false, float><<<GB, 256, 0, stream>>>(x, Wt1, dinv, hn1);
  k_agg8<128, __half><<<(NN * 16 + 255) / 256, 256, 0, stream>>>(
      (const __half*)hn1, rowptr, csr, dinv, b1, (__half*)a1);

  // layer 2: hn2 = (relu(a1) @ W2) * dinv ; out = dinv*(self + gather) + b2
  gemm_mfma<64, true, f16><<<GB, 256, 0, stream>>>(a1, Wt2, dinv, hn2);
  k_agg8<64, float><<<(NN * 8 + 255) / 256, 256, 0, stream>>>(
      (const __half*)hn2, rowptr, csr, dinv, b2, out);
}

// Round 13
// 219.508 us; speedup vs baseline: 2.3702x; 1.0324x over previous
//
#include <hip/hip_runtime.h>
#include <hip/hip_fp16.h>

#define NN 100000
#define NSB 256            // dst windows (one ownership block each)
#define WPS2 391           // dst nodes per window (ceil(NN/NSB))
#define CAP2 8192          // edge capacity per window (mean 6256)
#define EPB 16             // edges per thread in split

typedef _Float16 f16;
typedef _Float16 f16x8 __attribute__((ext_vector_type(8)));
typedef float f32x4 __attribute__((ext_vector_type(4)));

__device__ __forceinline__ int eload(const void* e, long i, int is64) {
  if (is64) return (int)((const long long*)e)[i];
  return ((const int*)e)[i];
}

// ---------------------------------------------------------------------------
// Block 0: dtype sniff (odd words zero => int64) + padded-cursor init.
// Blocks 1..24: weight prep Wt[n][k] fp16 from W[k][n] fp32 (both layers).
// bcur2 is PADDED: counter w lives at bcur2[w*16] (own 64B line).
// ---------------------------------------------------------------------------
__global__ __launch_bounds__(1024) void k_prep(const unsigned* __restrict__ e,
                                               int* __restrict__ flag,
                                               int* __restrict__ bcur2,
                                               const float* __restrict__ W1,
                                               const float* __restrict__ W2,
                                               f16* __restrict__ Wt1,
                                               f16* __restrict__ Wt2) {
  const int t = threadIdx.x;
  if (blockIdx.x == 0) {
    __shared__ unsigned red[1024];
    if (t < NSB) bcur2[t * 16] = t * CAP2;
    unsigned acc = e[1 + 2 * t] | e[1 + 2 * t + 2048];
    red[t] = acc;
    __syncthreads();
    for (int off = 512; off > 0; off >>= 1) {
      if (t < off) red[t] |= red[t + off];
      __syncthreads();
    }
    if (t == 0) *flag = (red[0] == 0) ? 1 : 0;  // 1 => int64
  } else {
    int idx = (blockIdx.x - 1) * 1024 + t;
    if (idx < 128 * 128) {
      int k = idx / 128, n = idx % 128;
      Wt1[n * 128 + k] = (f16)W1[idx];
    } else {
      int i2 = idx - 128 * 128;
      if (i2 < 128 * 64) {
        int k = i2 / 64, n = i2 % 64;
        Wt2[n * 128 + k] = (f16)W2[i2];
      }
    }
  }
}

// ---------------------------------------------------------------------------
// 256-way multi-split by dst window; output PACKED: (dloc<<17)|src.
// ---------------------------------------------------------------------------
__global__ __launch_bounds__(256) void k_split(const void* __restrict__ e,
                                               const int* __restrict__ flag,
                                               int E, int* __restrict__ bcur2,
                                               int* __restrict__ pk) {
  __shared__ int hist[NSB];
  const int tid = threadIdx.x;
  const long b0 = (long)blockIdx.x * (256 * EPB);
  const int is64 = *flag;
  hist[tid] = 0;
  __syncthreads();

  int sv[EPB], dv[EPB];
#pragma unroll
  for (int j = 0; j < EPB; ++j) {
    long idx = b0 + j * 256 + tid;
    int s = 0, d = -1;
    if (idx < E) {
      s = eload(e, idx, is64);
      d = eload(e, (long)E + idx, is64);
    }
    sv[j] = s; dv[j] = d;
    if (d >= 0) atomicAdd(&hist[(unsigned)d / WPS2], 1);
  }
  __syncthreads();
  {
    int c = hist[tid];
    int base = (c > 0) ? atomicAdd(&bcur2[tid * 16], c) : 0;
    __syncthreads();
    hist[tid] = base;
  }
  __syncthreads();
#pragma unroll
  for (int j = 0; j < EPB; ++j) {
    int d = dv[j];
    if (d < 0) continue;
    int w = (unsigned)d / WPS2;
    int dloc = d - w * WPS2;
    int pos = atomicAdd(&hist[w], 1);
    pk[pos] = (dloc << 17) | sv[j];
  }
}

// scan of 256 window totals -> wbase; rowptr[NN]=E
__global__ __launch_bounds__(256) void k_wscan(const int* __restrict__ bcur2,
                                               int* __restrict__ wbase,
                                               int* __restrict__ rowptr, int E) {
  __shared__ int sm[NSB];
  int t = threadIdx.x;
  int c = bcur2[t * 16] - t * CAP2;
  sm[t] = c;
  __syncthreads();
  for (int off = 1; off < NSB; off <<= 1) {
    int a = (t >= off) ? sm[t - off] : 0;
    __syncthreads();
    sm[t] += a;
    __syncthreads();
  }
  wbase[t] = sm[t] - c;
  if (t == 0) rowptr[NN] = E;
}

// ---------------------------------------------------------------------------
// Fused per-window build: LDS hist -> LDS scan -> rowptr+dinv -> csr replay.
// ---------------------------------------------------------------------------
__global__ __launch_bounds__(256) void k_build(const int* __restrict__ pk,
                                               const int* __restrict__ bcur2,
                                               const int* __restrict__ wbase,
                                               int* __restrict__ rowptr,
                                               float* __restrict__ dinv,
                                               int* __restrict__ csr) {
  __shared__ int lc[512];
  __shared__ int cur[512];
  const int tid = threadIdx.x;
  const int b = blockIdx.x;
  const int nlo = b * WPS2;
  const int nhi = (nlo + WPS2 < NN) ? nlo + WPS2 : NN;
  const int nw = nhi - nlo;
  lc[tid] = 0; lc[tid + 256] = 0;
  __syncthreads();
  const int cnt = bcur2[b * 16] - b * CAP2;
  const long s0 = (long)b * CAP2;
  for (int i = tid; i < cnt; i += 256)
    atomicAdd(&lc[(unsigned)pk[s0 + i] >> 17], 1);
  __syncthreads();
  for (int off = 1; off < 512; off <<= 1) {
    int a0 = (tid >= off) ? lc[tid - off] : 0;
    int a1 = (tid + 256 >= off) ? lc[tid + 256 - off] : 0;
    __syncthreads();
    lc[tid] += a0; lc[tid + 256] += a1;
    __syncthreads();
  }
  const int wb = wbase[b];
#pragma unroll
  for (int h = 0; h < 2; ++h) {
    int j = tid + h * 256;
    if (j < nw) {
      int inc = lc[j];
      int c = inc - (j > 0 ? lc[j - 1] : 0);
      int ex = wb + inc - c;
      rowptr[nlo + j] = ex;
      dinv[nlo + j] = rsqrtf((float)c + 1.0f);  // +1 self-loop
      cur[j] = ex;
    }
  }
  __syncthreads();
  for (int i = tid; i < cnt; i += 256) {
    int p = pk[s0 + i];
    int pos = atomicAdd(&cur[(unsigned)p >> 17], 1);
    csr[pos] = p & 0x1FFFF;
  }
}

// ---------------------------------------------------------------------------
// MFMA GEMM: Y[row] = ((relu?)X[row] @ W) * dinv[row], fp16 out.
// ---------------------------------------------------------------------------
template <int COUT, bool RELU, typename TIN>
__global__ __launch_bounds__(256) void gemm_mfma(const TIN* __restrict__ X,
                                                 const f16* __restrict__ Wt,
                                                 const float* __restrict__ dinv,
                                                 f16* __restrict__ Y) {
  constexpr int NF = COUT / 16;
  __shared__ f16 Al[128 * 128];
  __shared__ f16 Bl[COUT * 128];
  const int tid = threadIdx.x;
  const long row0 = (long)blockIdx.x * 128;

  for (int c = tid; c < COUT * 16; c += 256) {
    int n = c >> 4, g = c & 15;
    f16x8 v = *(const f16x8*)&Wt[n * 128 + g * 8];
    *(f16x8*)((char*)Bl + n * 256 + ((g * 16) ^ ((n & 7) << 4))) = v;
  }
  for (int c = tid; c < 2048; c += 256) {
    int r = c >> 4, g = c & 15;
    long grow = row0 + r;
    f16x8 v;
    if (grow < NN) {
      if constexpr (sizeof(TIN) == 4) {
        const float4* p = (const float4*)&X[grow * 128 + g * 8];
        float4 p0 = p[0], p1 = p[1];
        float f[8] = {p0.x, p0.y, p0.z, p0.w, p1.x, p1.y, p1.z, p1.w};
#pragma unroll
        for (int j = 0; j < 8; ++j) {
          float t = RELU ? fmaxf(f[j], 0.f) : f[j];
          v[j] = (f16)t;
        }
      } else {
        v = *(const f16x8*)&X[grow * 128 + g * 8];
        if (RELU) {
#pragma unroll
          for (int j = 0; j < 8; ++j) v[j] = v[j] > (f16)0 ? v[j] : (f16)0;
        }
      }
    } else {
#pragma unroll
      for (int j = 0; j < 8; ++j) v[j] = (f16)0;
    }
    *(f16x8*)((char*)Al + r * 256 + ((g * 16) ^ ((r & 7) << 4))) = v;
  }
  __syncthreads();

  const int l = tid & 63, w = tid >> 6;
  const int lm = l & 15, lg = l >> 4;
  const int r0 = w * 32 + lm, r1 = r0 + 16;

  f32x4 acc0[NF], acc1[NF];
#pragma unroll
  for (int nf = 0; nf < NF; ++nf) { acc0[nf] = (f32x4)(0.f); acc1[nf] = (f32x4)(0.f); }

#pragma unroll
  for (int kk = 0; kk < 4; ++kk) {
    const int kb = kk * 64 + lg * 16;
    f16x8 a0 = *(const f16x8*)((const char*)Al + r0 * 256 + (kb ^ ((r0 & 7) << 4)));
    f16x8 a1 = *(const f16x8*)((const char*)Al + r1 * 256 + (kb ^ ((r1 & 7) << 4)));
#pragma unroll
    for (int nf = 0; nf < NF; ++nf) {
      int n = nf * 16 + lm;
      f16x8 b = *(const f16x8*)((const char*)Bl + n * 256 + (kb ^ ((n & 7) << 4)));
      acc0[nf] = __builtin_amdgcn_mfma_f32_16x16x32_f16(a0, b, acc0[nf], 0, 0, 0);
      acc1[nf] = __builtin_amdgcn_mfma_f32_16x16x32_f16(a1, b, acc1[nf], 0, 0, 0);
    }
  }

#pragma unroll
  for (int reg = 0; reg < 4; ++reg) {
    long gr0 = row0 + w * 32 + lg * 4 + reg;
    long gr1 = gr0 + 16;
    float d0 = (gr0 < NN) ? dinv[gr0] : 0.f;
    float d1 = (gr1 < NN) ? dinv[gr1] : 0.f;
#pragma unroll
    for (int nf = 0; nf < NF; ++nf) {
      if (gr0 < NN) Y[gr0 * COUT + nf * 16 + lm] = (f16)(acc0[nf][reg] * d0);
      if (gr1 < NN) Y[gr1 * COUT + nf * 16 + lm] = (f16)(acc1[nf][reg] * d1);
    }
  }
}

// ---------------------------------------------------------------------------
// Gather agg, 8-deep pipeline, 1 row per TP-thread group (R9 structure —
// at the random-row fabric ceiling with floor traffic). Plain cached loads:
// csr lines have real cross-row reuse (R12 NT experiment: +90MB FETCH).
// ---------------------------------------------------------------------------
__device__ __forceinline__ void acc8f(float* acc, const __half* p) {
  float4 raw = *(const float4*)p;
  const __half2* h = (const __half2*)&raw;
#pragma unroll
  for (int q = 0; q < 4; ++q) {
    float2 f = __half22float2(h[q]);
    acc[2 * q] += f.x; acc[2 * q + 1] += f.y;
  }
}

template <int C, typename TOUT>
__global__ __launch_bounds__(256) void k_agg8(const __half* __restrict__ hn,
                                              const int* __restrict__ rowptr,
                                              const int* __restrict__ csr,
                                              const float* __restrict__ dinv,
                                              const float* __restrict__ bias,
                                              TOUT* __restrict__ out) {
  constexpr int TP = C / 8;
  long t = (long)blockIdx.x * 256 + threadIdx.x;
  int d = (int)(t / TP);
  if (d >= NN) return;
  int c8 = (int)(t % TP) * 8;

  float acc[8] = {0, 0, 0, 0, 0, 0, 0, 0};
  acc8f(acc, &hn[(long)d * C + c8]);  // self-loop message
  int e = rowptr[d];
  const int end = rowptr[d + 1];

  for (; e + 8 <= end; e += 8) {
    int s[8];
#pragma unroll
    for (int u = 0; u < 8; ++u) s[u] = csr[e + u];
    float4 r[8];
#pragma unroll
    for (int u = 0; u < 8; ++u) r[u] = *(const float4*)&hn[(long)s[u] * C + c8];
#pragma unroll
    for (int u = 0; u < 8; ++u) {
      const __half2* h = (const __half2*)&r[u];
#pragma unroll
      for (int q = 0; q < 4; ++q) {
        float2 f = __half22float2(h[q]);
        acc[2 * q] += f.x; acc[2 * q + 1] += f.y;
      }
    }
  }
  if (e + 4 <= end) {
    int s[4];
#pragma unroll
    for (int u = 0; u < 4; ++u) s[u] = csr[e + u];
    float4 r[4];
#pragma unroll
    for (int u = 0; u < 4; ++u) r[u] = *(const float4*)&hn[(long)s[u] * C + c8];
#pragma unroll
    for (int u = 0; u < 4; ++u) {
      const __half2* h = (const __half2*)&r[u];
#pragma unroll
      for (int q = 0; q < 4; ++q) {
        float2 f = __half22float2(h[q]);
        acc[2 * q] += f.x; acc[2 * q + 1] += f.y;
      }
    }
    e += 4;
  }
  for (; e < end; ++e) acc8f(acc, &hn[(long)csr[e] * C + c8]);

  float dd = dinv[d];
  float4 bv0 = *(const float4*)&bias[c8];
  float4 bv1 = *(const float4*)&bias[c8 + 4];
  float o[8];
  o[0] = acc[0] * dd + bv0.x; o[1] = acc[1] * dd + bv0.y;
  o[2] = acc[2] * dd + bv0.z; o[3] = acc[3] * dd + bv0.w;
  o[4] = acc[4] * dd + bv1.x; o[5] = acc[5] * dd + bv1.y;
  o[6] = acc[6] * dd + bv1.z; o[7] = acc[7] * dd + bv1.w;

  if constexpr (sizeof(TOUT) == 2) {
    __half2 hp[4];
    hp[0] = __floats2half2_rn(o[0], o[1]);
    hp[1] = __floats2half2_rn(o[2], o[3]);
    hp[2] = __floats2half2_rn(o[4], o[5]);
    hp[3] = __floats2half2_rn(o[6], o[7]);
    *(float4*)&out[(long)d * C + c8] = *(float4*)hp;
  } else {
    *(float4*)&out[(long)d * C + c8]     = make_float4(o[0], o[1], o[2], o[3]);
    *(float4*)&out[(long)d * C + c8 + 4] = make_float4(o[4], o[5], o[6], o[7]);
  }
}

extern "C" void kernel_launch(void* const* d_in, const int* in_sizes, int n_in,
                              void* d_out, int out_size, void* d_ws, size_t ws_size,
                              hipStream_t stream) {
  const float* x  = (const float*)d_in[0];
  const void*  ep = d_in[1];
  const float* W1 = (const float*)d_in[2];
  const float* b1 = (const float*)d_in[3];
  const float* W2 = (const float*)d_in[4];
  const float* b2 = (const float*)d_in[5];
  float* out = (float*)d_out;
  const int E = in_sizes[1] / 2;

  // workspace layout (int-element offsets)
  float*  wsf    = (float*)d_ws;
  int*    wsi    = (int*)d_ws;
  int*    flag   = wsi;                        // [0]
  int*    bcur2  = wsi + 64;                   // 256*16 padded (4096)
  int*    wbase  = wsi + 4224;                 // 256
  float*  dinv   = wsf + 4480;                 // 100000
  int*    rowptr = wsi + 104480;               // 100001
  f16*    Wt1    = (f16*)(wsi + 204496);       // 16384 halves (8192 ints)
  f16*    Wt2    = (f16*)(wsi + 212688);       // 8192 halves (4096 ints)
  int*    csr    = wsi + 216784;               // 1600000
  int*    pk     = wsi + 1816784;              // 256*CAP2 = 2097152
  f16*    hn1    = (f16*)(wsi + 3913936);      // 12.8M halves (6.4M ints)
  f16*    a1     = (f16*)(wsi + 10313936);     // 12.8M halves
  f16*    hn2    = hn1;                        // hn1 dead once a1 built

  const int SB = (E + 256 * EPB - 1) / (256 * EPB);  // 391
  const int GB = (NN + 127) / 128;                   // 782

  k_prep<<<25, 1024, 0, stream>>>((const unsigned*)ep, flag, bcur2, W1, W2, Wt1, Wt2);
  k_split<<<SB, 256, 0, stream>>>(ep, flag, E, bcur2, pk);
  k_wscan<<<1, 256, 0, stream>>>(bcur2, wbase, rowptr, E);
  k_build<<<NSB, 256, 0, stream>>>(pk, bcur2, wbase, rowptr, dinv, csr);

  // layer 1: hn1 = (x @ W1) * dinv ; a1 = dinv*(self + gather) + b1
  gemm_mfma<128, false, float><<<GB, 256, 0, stream>>>(x, Wt1, dinv, hn1);
  k_agg8<128, __half><<<(NN * 16 + 255) / 256, 256, 0, stream>>>(
      (const __half*)hn1, rowptr, csr, dinv, b1, (__half*)a1);

  // layer 2: hn2 = (relu(a1) @ W2) * dinv ; out = dinv*(self + gather) + b2
  gemm_mfma<64, true, f16><<<GB, 256, 0, stream>>>(a1, Wt2, dinv, hn2);
  k_agg8<64, float><<<(NN * 8 + 255) / 256, 256, 0, stream>>>(
      (const __half*)hn2, rowptr, csr, dinv, b2, out);
}

// Round 14
// 182.316 us; speedup vs baseline: 2.8537x; 1.2040x over previous
//
#include <hip/hip_runtime.h>
#include <hip/hip_fp16.h>

#define NN 100000
#define NSB 256            // dst windows (one ownership block each)
#define WPS2 391           // dst nodes per window (ceil(NN/NSB))
#define CAP2 8192          // edge capacity per window (mean 6256)
#define EPB 16             // edges per thread in split

typedef _Float16 f16;
typedef _Float16 f16x8 __attribute__((ext_vector_type(8)));
typedef float f32x4 __attribute__((ext_vector_type(4)));

__device__ __forceinline__ int eload(const void* e, long i, int is64) {
  if (is64) return (int)((const long long*)e)[i];
  return ((const int*)e)[i];
}

// ---------------------------------------------------------------------------
// Block 0: dtype sniff (odd words zero => int64) + padded-cursor init.
// Blocks 1..24: weight prep Wt[n][k] fp16 from W[k][n] fp32 (both layers).
// bcur2 is PADDED: counter w lives at bcur2[w*16] (own 64B line).
// ---------------------------------------------------------------------------
__global__ __launch_bounds__(1024) void k_prep(const unsigned* __restrict__ e,
                                               int* __restrict__ flag,
                                               int* __restrict__ bcur2,
                                               const float* __restrict__ W1,
                                               const float* __restrict__ W2,
                                               f16* __restrict__ Wt1,
                                               f16* __restrict__ Wt2) {
  const int t = threadIdx.x;
  if (blockIdx.x == 0) {
    __shared__ unsigned red[1024];
    if (t < NSB) bcur2[t * 16] = t * CAP2;
    unsigned acc = e[1 + 2 * t] | e[1 + 2 * t + 2048];
    red[t] = acc;
    __syncthreads();
    for (int off = 512; off > 0; off >>= 1) {
      if (t < off) red[t] |= red[t + off];
      __syncthreads();
    }
    if (t == 0) *flag = (red[0] == 0) ? 1 : 0;  // 1 => int64
  } else {
    int idx = (blockIdx.x - 1) * 1024 + t;
    if (idx < 128 * 128) {
      int k = idx / 128, n = idx % 128;
      Wt1[n * 128 + k] = (f16)W1[idx];
    } else {
      int i2 = idx - 128 * 128;
      if (i2 < 128 * 64) {
        int k = i2 / 64, n = i2 % 64;
        Wt2[n * 128 + k] = (f16)W2[i2];
      }
    }
  }
}

// ---------------------------------------------------------------------------
// 256-way multi-split by dst window; output PACKED: (dloc<<17)|src.
// ---------------------------------------------------------------------------
__global__ __launch_bounds__(256) void k_split(const void* __restrict__ e,
                                               const int* __restrict__ flag,
                                               int E, int* __restrict__ bcur2,
                                               int* __restrict__ pk) {
  __shared__ int hist[NSB];
  const int tid = threadIdx.x;
  const long b0 = (long)blockIdx.x * (256 * EPB);
  const int is64 = *flag;
  hist[tid] = 0;
  __syncthreads();

  int sv[EPB], dv[EPB];
#pragma unroll
  for (int j = 0; j < EPB; ++j) {
    long idx = b0 + j * 256 + tid;
    int s = 0, d = -1;
    if (idx < E) {
      s = eload(e, idx, is64);
      d = eload(e, (long)E + idx, is64);
    }
    sv[j] = s; dv[j] = d;
    if (d >= 0) atomicAdd(&hist[(unsigned)d / WPS2], 1);
  }
  __syncthreads();
  {
    int c = hist[tid];
    int base = (c > 0) ? atomicAdd(&bcur2[tid * 16], c) : 0;
    __syncthreads();
    hist[tid] = base;
  }
  __syncthreads();
#pragma unroll
  for (int j = 0; j < EPB; ++j) {
    int d = dv[j];
    if (d < 0) continue;
    int w = (unsigned)d / WPS2;
    int dloc = d - w * WPS2;
    int pos = atomicAdd(&hist[w], 1);
    pk[pos] = (dloc << 17) | sv[j];
  }
}

// scan of 256 window totals -> wbase; rowptr[NN]=E
__global__ __launch_bounds__(256) void k_wscan(const int* __restrict__ bcur2,
                                               int* __restrict__ wbase,
                                               int* __restrict__ rowptr, int E) {
  __shared__ int sm[NSB];
  int t = threadIdx.x;
  int c = bcur2[t * 16] - t * CAP2;
  sm[t] = c;
  __syncthreads();
  for (int off = 1; off < NSB; off <<= 1) {
    int a = (t >= off) ? sm[t - off] : 0;
    __syncthreads();
    sm[t] += a;
    __syncthreads();
  }
  wbase[t] = sm[t] - c;
  if (t == 0) rowptr[NN] = E;
}

// ---------------------------------------------------------------------------
// Fused per-window build: LDS hist -> LDS scan -> rowptr+dinv -> csr replay.
// ---------------------------------------------------------------------------
__global__ __launch_bounds__(256) void k_build(const int* __restrict__ pk,
                                               const int* __restrict__ bcur2,
                                               const int* __restrict__ wbase,
                                               int* __restrict__ rowptr,
                                               float* __restrict__ dinv,
                                               int* __restrict__ csr) {
  __shared__ int lc[512];
  __shared__ int cur[512];
  const int tid = threadIdx.x;
  const int b = blockIdx.x;
  const int nlo = b * WPS2;
  const int nhi = (nlo + WPS2 < NN) ? nlo + WPS2 : NN;
  const int nw = nhi - nlo;
  lc[tid] = 0; lc[tid + 256] = 0;
  __syncthreads();
  const int cnt = bcur2[b * 16] - b * CAP2;
  const long s0 = (long)b * CAP2;
  for (int i = tid; i < cnt; i += 256)
    atomicAdd(&lc[(unsigned)pk[s0 + i] >> 17], 1);
  __syncthreads();
  for (int off = 1; off < 512; off <<= 1) {
    int a0 = (tid >= off) ? lc[tid - off] : 0;
    int a1 = (tid + 256 >= off) ? lc[tid + 256 - off] : 0;
    __syncthreads();
    lc[tid] += a0; lc[tid + 256] += a1;
    __syncthreads();
  }
  const int wb = wbase[b];
#pragma unroll
  for (int h = 0; h < 2; ++h) {
    int j = tid + h * 256;
    if (j < nw) {
      int inc = lc[j];
      int c = inc - (j > 0 ? lc[j - 1] : 0);
      int ex = wb + inc - c;
      rowptr[nlo + j] = ex;
      dinv[nlo + j] = rsqrtf((float)c + 1.0f);  // +1 self-loop
      cur[j] = ex;
    }
  }
  __syncthreads();
  for (int i = tid; i < cnt; i += 256) {
    int p = pk[s0 + i];
    int pos = atomicAdd(&cur[(unsigned)p >> 17], 1);
    csr[pos] = p & 0x1FFFF;
  }
}

// ---------------------------------------------------------------------------
// MFMA GEMM: Y[row] = ((relu?)X[row] @ W) * dinv[row], fp16 out.
// ---------------------------------------------------------------------------
template <int COUT, bool RELU, typename TIN>
__global__ __launch_bounds__(256) void gemm_mfma(const TIN* __restrict__ X,
                                                 const f16* __restrict__ Wt,
                                                 const float* __restrict__ dinv,
                                                 f16* __restrict__ Y) {
  constexpr int NF = COUT / 16;
  __shared__ f16 Al[128 * 128];
  __shared__ f16 Bl[COUT * 128];
  const int tid = threadIdx.x;
  const long row0 = (long)blockIdx.x * 128;

  for (int c = tid; c < COUT * 16; c += 256) {
    int n = c >> 4, g = c & 15;
    f16x8 v = *(const f16x8*)&Wt[n * 128 + g * 8];
    *(f16x8*)((char*)Bl + n * 256 + ((g * 16) ^ ((n & 7) << 4))) = v;
  }
  for (int c = tid; c < 2048; c += 256) {
    int r = c >> 4, g = c & 15;
    long grow = row0 + r;
    f16x8 v;
    if (grow < NN) {
      if constexpr (sizeof(TIN) == 4) {
        const float4* p = (const float4*)&X[grow * 128 + g * 8];
        float4 p0 = p[0], p1 = p[1];
        float f[8] = {p0.x, p0.y, p0.z, p0.w, p1.x, p1.y, p1.z, p1.w};
#pragma unroll
        for (int j = 0; j < 8; ++j) {
          float t = RELU ? fmaxf(f[j], 0.f) : f[j];
          v[j] = (f16)t;
        }
      } else {
        v = *(const f16x8*)&X[grow * 128 + g * 8];
        if (RELU) {
#pragma unroll
          for (int j = 0; j < 8; ++j) v[j] = v[j] > (f16)0 ? v[j] : (f16)0;
        }
      }
    } else {
#pragma unroll
      for (int j = 0; j < 8; ++j) v[j] = (f16)0;
    }
    *(f16x8*)((char*)Al + r * 256 + ((g * 16) ^ ((r & 7) << 4))) = v;
  }
  __syncthreads();

  const int l = tid & 63, w = tid >> 6;
  const int lm = l & 15, lg = l >> 4;
  const int r0 = w * 32 + lm, r1 = r0 + 16;

  f32x4 acc0[NF], acc1[NF];
#pragma unroll
  for (int nf = 0; nf < NF; ++nf) { acc0[nf] = (f32x4)(0.f); acc1[nf] = (f32x4)(0.f); }

#pragma unroll
  for (int kk = 0; kk < 4; ++kk) {
    const int kb = kk * 64 + lg * 16;
    f16x8 a0 = *(const f16x8*)((const char*)Al + r0 * 256 + (kb ^ ((r0 & 7) << 4)));
    f16x8 a1 = *(const f16x8*)((const char*)Al + r1 * 256 + (kb ^ ((r1 & 7) << 4)));
#pragma unroll
    for (int nf = 0; nf < NF; ++nf) {
      int n = nf * 16 + lm;
      f16x8 b = *(const f16x8*)((const char*)Bl + n * 256 + (kb ^ ((n & 7) << 4)));
      acc0[nf] = __builtin_amdgcn_mfma_f32_16x16x32_f16(a0, b, acc0[nf], 0, 0, 0);
      acc1[nf] = __builtin_amdgcn_mfma_f32_16x16x32_f16(a1, b, acc1[nf], 0, 0, 0);
    }
  }

#pragma unroll
  for (int reg = 0; reg < 4; ++reg) {
    long gr0 = row0 + w * 32 + lg * 4 + reg;
    long gr1 = gr0 + 16;
    float d0 = (gr0 < NN) ? dinv[gr0] : 0.f;
    float d1 = (gr1 < NN) ? dinv[gr1] : 0.f;
#pragma unroll
    for (int nf = 0; nf < NF; ++nf) {
      if (gr0 < NN) Y[gr0 * COUT + nf * 16 + lm] = (f16)(acc0[nf][reg] * d0);
      if (gr1 < NN) Y[gr1 * COUT + nf * 16 + lm] = (f16)(acc1[nf][reg] * d1);
    }
  }
}

// ---------------------------------------------------------------------------
// Gather agg, 8-deep pipeline, 1 row per TP-thread group (R9 structure —
// at the random-row fabric ceiling with floor traffic). Plain cached loads.
// hn MUST be 256B-aligned: rows at 64-mod-128 cost 1.5x HBM sectors (R13).
// ---------------------------------------------------------------------------
__device__ __forceinline__ void acc8f(float* acc, const __half* p) {
  float4 raw = *(const float4*)p;
  const __half2* h = (const __half2*)&raw;
#pragma unroll
  for (int q = 0; q < 4; ++q) {
    float2 f = __half22float2(h[q]);
    acc[2 * q] += f.x; acc[2 * q + 1] += f.y;
  }
}

template <int C, typename TOUT>
__global__ __launch_bounds__(256) void k_agg8(const __half* __restrict__ hn,
                                              const int* __restrict__ rowptr,
                                              const int* __restrict__ csr,
                                              const float* __restrict__ dinv,
                                              const float* __restrict__ bias,
                                              TOUT* __restrict__ out) {
  constexpr int TP = C / 8;
  long t = (long)blockIdx.x * 256 + threadIdx.x;
  int d = (int)(t / TP);
  if (d >= NN) return;
  int c8 = (int)(t % TP) * 8;

  float acc[8] = {0, 0, 0, 0, 0, 0, 0, 0};
  acc8f(acc, &hn[(long)d * C + c8]);  // self-loop message
  int e = rowptr[d];
  const int end = rowptr[d + 1];

  for (; e + 8 <= end; e += 8) {
    int s[8];
#pragma unroll
    for (int u = 0; u < 8; ++u) s[u] = csr[e + u];
    float4 r[8];
#pragma unroll
    for (int u = 0; u < 8; ++u) r[u] = *(const float4*)&hn[(long)s[u] * C + c8];
#pragma unroll
    for (int u = 0; u < 8; ++u) {
      const __half2* h = (const __half2*)&r[u];
#pragma unroll
      for (int q = 0; q < 4; ++q) {
        float2 f = __half22float2(h[q]);
        acc[2 * q] += f.x; acc[2 * q + 1] += f.y;
      }
    }
  }
  if (e + 4 <= end) {
    int s[4];
#pragma unroll
    for (int u = 0; u < 4; ++u) s[u] = csr[e + u];
    float4 r[4];
#pragma unroll
    for (int u = 0; u < 4; ++u) r[u] = *(const float4*)&hn[(long)s[u] * C + c8];
#pragma unroll
    for (int u = 0; u < 4; ++u) {
      const __half2* h = (const __half2*)&r[u];
#pragma unroll
      for (int q = 0; q < 4; ++q) {
        float2 f = __half22float2(h[q]);
        acc[2 * q] += f.x; acc[2 * q + 1] += f.y;
      }
    }
    e += 4;
  }
  for (; e < end; ++e) acc8f(acc, &hn[(long)csr[e] * C + c8]);

  float dd = dinv[d];
  float4 bv0 = *(const float4*)&bias[c8];
  float4 bv1 = *(const float4*)&bias[c8 + 4];
  float o[8];
  o[0] = acc[0] * dd + bv0.x; o[1] = acc[1] * dd + bv0.y;
  o[2] = acc[2] * dd + bv0.z; o[3] = acc[3] * dd + bv0.w;
  o[4] = acc[4] * dd + bv1.x; o[5] = acc[5] * dd + bv1.y;
  o[6] = acc[6] * dd + bv1.z; o[7] = acc[7] * dd + bv1.w;

  if constexpr (sizeof(TOUT) == 2) {
    __half2 hp[4];
    hp[0] = __floats2half2_rn(o[0], o[1]);
    hp[1] = __floats2half2_rn(o[2], o[3]);
    hp[2] = __floats2half2_rn(o[4], o[5]);
    hp[3] = __floats2half2_rn(o[6], o[7]);
    *(float4*)&out[(long)d * C + c8] = *(float4*)hp;
  } else {
    *(float4*)&out[(long)d * C + c8]     = make_float4(o[0], o[1], o[2], o[3]);
    *(float4*)&out[(long)d * C + c8 + 4] = make_float4(o[4], o[5], o[6], o[7]);
  }
}

extern "C" void kernel_launch(void* const* d_in, const int* in_sizes, int n_in,
                              void* d_out, int out_size, void* d_ws, size_t ws_size,
                              hipStream_t stream) {
  const float* x  = (const float*)d_in[0];
  const void*  ep = d_in[1];
  const float* W1 = (const float*)d_in[2];
  const float* b1 = (const float*)d_in[3];
  const float* W2 = (const float*)d_in[4];
  const float* b2 = (const float*)d_in[5];
  float* out = (float*)d_out;
  const int E = in_sizes[1] / 2;

  // workspace layout — ALL int offsets are multiples of 64 (256B-aligned;
  // R13 post-mortem: hn rows at 64-mod-128 cost 1.5x HBM sectors on gather)
  float*  wsf    = (float*)d_ws;
  int*    wsi    = (int*)d_ws;
  int*    flag   = wsi;                        // [0]
  int*    bcur2  = wsi + 64;                   // 256*16 padded -> ends 4160
  int*    wbase  = wsi + 4224;                 // 256
  float*  dinv   = wsf + 4480;                 // 100000 -> ends 104480
  int*    rowptr = wsi + 104512;               // 100001 -> ends 204513
  f16*    Wt1    = (f16*)(wsi + 204544);       // 16384 halves (8192 ints)
  f16*    Wt2    = (f16*)(wsi + 212736);       // 8192 halves (4096 ints)
  int*    csr    = wsi + 216832;               // 1600000 -> ends 1816832
  int*    pk     = wsi + 1816832;              // 2097152 -> ends 3913984
  f16*    hn1    = (f16*)(wsi + 3913984);      // 12.8M halves -> ends 10313984
  f16*    a1     = (f16*)(wsi + 10313984);     // 12.8M halves -> ends 16713984
  f16*    hn2    = hn1;                        // hn1 dead once a1 built

  const int SB = (E + 256 * EPB - 1) / (256 * EPB);  // 391
  const int GB = (NN + 127) / 128;                   // 782

  k_prep<<<25, 1024, 0, stream>>>((const unsigned*)ep, flag, bcur2, W1, W2, Wt1, Wt2);
  k_split<<<SB, 256, 0, stream>>>(ep, flag, E, bcur2, pk);
  k_wscan<<<1, 256, 0, stream>>>(bcur2, wbase, rowptr, E);
  k_build<<<NSB, 256, 0, stream>>>(pk, bcur2, wbase, rowptr, dinv, csr);

  // layer 1: hn1 = (x @ W1) * dinv ; a1 = dinv*(self + gather) + b1
  gemm_mfma<128, false, float><<<GB, 256, 0, stream>>>(x, Wt1, dinv, hn1);
  k_agg8<128, __half><<<(NN * 16 + 255) / 256, 256, 0, stream>>>(
      (const __half*)hn1, rowptr, csr, dinv, b1, (__half*)a1);

  // layer 2: hn2 = (relu(a1) @ W2) * dinv ; out = dinv*(self + gather) + b2
  gemm_mfma<64, true, f16><<<GB, 256, 0, stream>>>(a1, Wt2, dinv, hn2);
  k_agg8<64, float><<<(NN * 8 + 255) / 256, 256, 0, stream>>>(
      (const __half*)hn2, rowptr, csr, dinv, b2, out);
}

// Round 15
// 181.343 us; speedup vs baseline: 2.8691x; 1.0054x over previous
//
#include <hip/hip_runtime.h>
#include <hip/hip_fp16.h>

#define NN 100000
#define NSB 256            // dst windows (one ownership block each)
#define WPS2 391           // dst nodes per window (ceil(NN/NSB))
#define CAP2 8192          // edge capacity per window (mean 6256)
#define EPB 16             // edges per thread in split

typedef _Float16 f16;
typedef _Float16 f16x8 __attribute__((ext_vector_type(8)));
typedef float f32x4 __attribute__((ext_vector_type(4)));

__device__ __forceinline__ int eload(const void* e, long i, int is64) {
  if (is64) return (int)((const long long*)e)[i];
  return ((const int*)e)[i];
}

// ---------------------------------------------------------------------------
// Block 0: dtype sniff (odd words zero => int64) + padded-cursor init.
// Blocks 1..24: weight prep Wt[n][k] fp16 from W[k][n] fp32 (both layers).
// bcur2 is PADDED: counter w lives at bcur2[w*16] (own 64B line).
// ---------------------------------------------------------------------------
__global__ __launch_bounds__(1024) void k_prep(const unsigned* __restrict__ e,
                                               int* __restrict__ flag,
                                               int* __restrict__ bcur2,
                                               const float* __restrict__ W1,
                                               const float* __restrict__ W2,
                                               f16* __restrict__ Wt1,
                                               f16* __restrict__ Wt2) {
  const int t = threadIdx.x;
  if (blockIdx.x == 0) {
    __shared__ unsigned red[1024];
    if (t < NSB) bcur2[t * 16] = t * CAP2;
    unsigned acc = e[1 + 2 * t] | e[1 + 2 * t + 2048];
    red[t] = acc;
    __syncthreads();
    for (int off = 512; off > 0; off >>= 1) {
      if (t < off) red[t] |= red[t + off];
      __syncthreads();
    }
    if (t == 0) *flag = (red[0] == 0) ? 1 : 0;  // 1 => int64
  } else {
    int idx = (blockIdx.x - 1) * 1024 + t;
    if (idx < 128 * 128) {
      int k = idx / 128, n = idx % 128;
      Wt1[n * 128 + k] = (f16)W1[idx];
    } else {
      int i2 = idx - 128 * 128;
      if (i2 < 128 * 64) {
        int k = i2 / 64, n = i2 % 64;
        Wt2[n * 128 + k] = (f16)W2[i2];
      }
    }
  }
}

// ---------------------------------------------------------------------------
// 256-way multi-split by dst window; output PACKED: (dloc<<17)|src.
// ---------------------------------------------------------------------------
__global__ __launch_bounds__(256) void k_split(const void* __restrict__ e,
                                               const int* __restrict__ flag,
                                               int E, int* __restrict__ bcur2,
                                               int* __restrict__ pk) {
  __shared__ int hist[NSB];
  const int tid = threadIdx.x;
  const long b0 = (long)blockIdx.x * (256 * EPB);
  const int is64 = *flag;
  hist[tid] = 0;
  __syncthreads();

  int sv[EPB], dv[EPB];
#pragma unroll
  for (int j = 0; j < EPB; ++j) {
    long idx = b0 + j * 256 + tid;
    int s = 0, d = -1;
    if (idx < E) {
      s = eload(e, idx, is64);
      d = eload(e, (long)E + idx, is64);
    }
    sv[j] = s; dv[j] = d;
    if (d >= 0) atomicAdd(&hist[(unsigned)d / WPS2], 1);
  }
  __syncthreads();
  {
    int c = hist[tid];
    int base = (c > 0) ? atomicAdd(&bcur2[tid * 16], c) : 0;
    __syncthreads();
    hist[tid] = base;
  }
  __syncthreads();
#pragma unroll
  for (int j = 0; j < EPB; ++j) {
    int d = dv[j];
    if (d < 0) continue;
    int w = (unsigned)d / WPS2;
    int dloc = d - w * WPS2;
    int pos = atomicAdd(&hist[w], 1);
    pk[pos] = (dloc << 17) | sv[j];
  }
}

// ---------------------------------------------------------------------------
// Fused per-window build: redundant 256-wide window scan (replaces k_wscan)
// -> LDS hist -> LDS scan -> rowptr+dinv -> csr replay via LDS cursors.
// ---------------------------------------------------------------------------
__global__ __launch_bounds__(256) void k_build(const int* __restrict__ pk,
                                               const int* __restrict__ bcur2,
                                               int* __restrict__ rowptr,
                                               float* __restrict__ dinv,
                                               int* __restrict__ csr) {
  __shared__ int ws[NSB];
  __shared__ int lc[512];
  __shared__ int cur[512];
  const int tid = threadIdx.x;
  const int b = blockIdx.x;
  const int nlo = b * WPS2;
  const int nhi = (nlo + WPS2 < NN) ? nlo + WPS2 : NN;
  const int nw = nhi - nlo;
  ws[tid] = bcur2[tid * 16] - tid * CAP2;  // window totals
  lc[tid] = 0; lc[tid + 256] = 0;
  __syncthreads();
  const int cnt = ws[b];
  // inclusive scan of window totals (redundant per block; 256 wide)
  for (int off = 1; off < NSB; off <<= 1) {
    int a = (tid >= off) ? ws[tid - off] : 0;
    __syncthreads();
    ws[tid] += a;
    __syncthreads();
  }
  const int wb = ws[b] - cnt;  // exclusive prefix = this window's csr base
  if (b == NSB - 1 && tid == 0) rowptr[NN] = ws[NSB - 1];

  const long s0 = (long)b * CAP2;
  for (int i = tid; i < cnt; i += 256)
    atomicAdd(&lc[(unsigned)pk[s0 + i] >> 17], 1);
  __syncthreads();
  for (int off = 1; off < 512; off <<= 1) {
    int a0 = (tid >= off) ? lc[tid - off] : 0;
    int a1 = (tid + 256 >= off) ? lc[tid + 256 - off] : 0;
    __syncthreads();
    lc[tid] += a0; lc[tid + 256] += a1;
    __syncthreads();
  }
#pragma unroll
  for (int h = 0; h < 2; ++h) {
    int j = tid + h * 256;
    if (j < nw) {
      int inc = lc[j];
      int c = inc - (j > 0 ? lc[j - 1] : 0);
      int ex = wb + inc - c;
      rowptr[nlo + j] = ex;
      dinv[nlo + j] = rsqrtf((float)c + 1.0f);  // +1 self-loop
      cur[j] = ex;
    }
  }
  __syncthreads();
  for (int i = tid; i < cnt; i += 256) {
    int p = pk[s0 + i];
    int pos = atomicAdd(&cur[(unsigned)p >> 17], 1);
    csr[pos] = p & 0x1FFFF;
  }
}

// ---------------------------------------------------------------------------
// MFMA GEMM: Y[row] = ((relu?)X[row] @ W) * dinv[row], fp16 out.
// ---------------------------------------------------------------------------
template <int COUT, bool RELU, typename TIN>
__global__ __launch_bounds__(256) void gemm_mfma(const TIN* __restrict__ X,
                                                 const f16* __restrict__ Wt,
                                                 const float* __restrict__ dinv,
                                                 f16* __restrict__ Y) {
  constexpr int NF = COUT / 16;
  __shared__ f16 Al[128 * 128];
  __shared__ f16 Bl[COUT * 128];
  const int tid = threadIdx.x;
  const long row0 = (long)blockIdx.x * 128;

  for (int c = tid; c < COUT * 16; c += 256) {
    int n = c >> 4, g = c & 15;
    f16x8 v = *(const f16x8*)&Wt[n * 128 + g * 8];
    *(f16x8*)((char*)Bl + n * 256 + ((g * 16) ^ ((n & 7) << 4))) = v;
  }
  for (int c = tid; c < 2048; c += 256) {
    int r = c >> 4, g = c & 15;
    long grow = row0 + r;
    f16x8 v;
    if (grow < NN) {
      if constexpr (sizeof(TIN) == 4) {
        const float4* p = (const float4*)&X[grow * 128 + g * 8];
        float4 p0 = p[0], p1 = p[1];
        float f[8] = {p0.x, p0.y, p0.z, p0.w, p1.x, p1.y, p1.z, p1.w};
#pragma unroll
        for (int j = 0; j < 8; ++j) {
          float t = RELU ? fmaxf(f[j], 0.f) : f[j];
          v[j] = (f16)t;
        }
      } else {
        v = *(const f16x8*)&X[grow * 128 + g * 8];
        if (RELU) {
#pragma unroll
          for (int j = 0; j < 8; ++j) v[j] = v[j] > (f16)0 ? v[j] : (f16)0;
        }
      }
    } else {
#pragma unroll
      for (int j = 0; j < 8; ++j) v[j] = (f16)0;
    }
    *(f16x8*)((char*)Al + r * 256 + ((g * 16) ^ ((r & 7) << 4))) = v;
  }
  __syncthreads();

  const int l = tid & 63, w = tid >> 6;
  const int lm = l & 15, lg = l >> 4;
  const int r0 = w * 32 + lm, r1 = r0 + 16;

  f32x4 acc0[NF], acc1[NF];
#pragma unroll
  for (int nf = 0; nf < NF; ++nf) { acc0[nf] = (f32x4)(0.f); acc1[nf] = (f32x4)(0.f); }

#pragma unroll
  for (int kk = 0; kk < 4; ++kk) {
    const int kb = kk * 64 + lg * 16;
    f16x8 a0 = *(const f16x8*)((const char*)Al + r0 * 256 + (kb ^ ((r0 & 7) << 4)));
    f16x8 a1 = *(const f16x8*)((const char*)Al + r1 * 256 + (kb ^ ((r1 & 7) << 4)));
#pragma unroll
    for (int nf = 0; nf < NF; ++nf) {
      int n = nf * 16 + lm;
      f16x8 b = *(const f16x8*)((const char*)Bl + n * 256 + (kb ^ ((n & 7) << 4)));
      acc0[nf] = __builtin_amdgcn_mfma_f32_16x16x32_f16(a0, b, acc0[nf], 0, 0, 0);
      acc1[nf] = __builtin_amdgcn_mfma_f32_16x16x32_f16(a1, b, acc1[nf], 0, 0, 0);
    }
  }

#pragma unroll
  for (int reg = 0; reg < 4; ++reg) {
    long gr0 = row0 + w * 32 + lg * 4 + reg;
    long gr1 = gr0 + 16;
    float d0 = (gr0 < NN) ? dinv[gr0] : 0.f;
    float d1 = (gr1 < NN) ? dinv[gr1] : 0.f;
#pragma unroll
    for (int nf = 0; nf < NF; ++nf) {
      if (gr0 < NN) Y[gr0 * COUT + nf * 16 + lm] = (f16)(acc0[nf][reg] * d0);
      if (gr1 < NN) Y[gr1 * COUT + nf * 16 + lm] = (f16)(acc1[nf][reg] * d1);
    }
  }
}

// ---------------------------------------------------------------------------
// Gather agg, 8-deep pipeline, TP=C/4 (8B/lane): same floor traffic, but 2x
// waves vs the 16B/lane version -> 2x outstanding gathers per CU (the R14
// profile shows 45% occupancy + 50% HBM: latency-bound, wave-MLP is the lever).
// hn MUST be 256B-aligned (R13: rows at 64-mod-128 cost 1.5x HBM sectors).
// ---------------------------------------------------------------------------
__device__ __forceinline__ void acc4f(float* acc, const __half* p) {
  float2 raw = *(const float2*)p;
  const __half2* h = (const __half2*)&raw;
  float2 f0 = __half22float2(h[0]);
  float2 f1 = __half22float2(h[1]);
  acc[0] += f0.x; acc[1] += f0.y; acc[2] += f1.x; acc[3] += f1.y;
}

template <int C, typename TOUT>
__global__ __launch_bounds__(256) void k_agg4(const __half* __restrict__ hn,
                                              const int* __restrict__ rowptr,
                                              const int* __restrict__ csr,
                                              const float* __restrict__ dinv,
                                              const float* __restrict__ bias,
                                              TOUT* __restrict__ out) {
  constexpr int TP = C / 4;
  long t = (long)blockIdx.x * 256 + threadIdx.x;
  int d = (int)(t / TP);
  if (d >= NN) return;
  int c4 = (int)(t % TP) * 4;

  float acc[4] = {0, 0, 0, 0};
  acc4f(acc, &hn[(long)d * C + c4]);  // self-loop message
  int e = rowptr[d];
  const int end = rowptr[d + 1];

  for (; e + 8 <= end; e += 8) {
    int s[8];
#pragma unroll
    for (int u = 0; u < 8; ++u) s[u] = csr[e + u];
    float2 r[8];
#pragma unroll
    for (int u = 0; u < 8; ++u) r[u] = *(const float2*)&hn[(long)s[u] * C + c4];
#pragma unroll
    for (int u = 0; u < 8; ++u) {
      const __half2* h = (const __half2*)&r[u];
      float2 f0 = __half22float2(h[0]);
      float2 f1 = __half22float2(h[1]);
      acc[0] += f0.x; acc[1] += f0.y; acc[2] += f1.x; acc[3] += f1.y;
    }
  }
  if (e + 4 <= end) {
    int s[4];
#pragma unroll
    for (int u = 0; u < 4; ++u) s[u] = csr[e + u];
    float2 r[4];
#pragma unroll
    for (int u = 0; u < 4; ++u) r[u] = *(const float2*)&hn[(long)s[u] * C + c4];
#pragma unroll
    for (int u = 0; u < 4; ++u) {
      const __half2* h = (const __half2*)&r[u];
      float2 f0 = __half22float2(h[0]);
      float2 f1 = __half22float2(h[1]);
      acc[0] += f0.x; acc[1] += f0.y; acc[2] += f1.x; acc[3] += f1.y;
    }
    e += 4;
  }
  for (; e < end; ++e) acc4f(acc, &hn[(long)csr[e] * C + c4]);

  float dd = dinv[d];
  float4 bv = *(const float4*)&bias[c4];
  float o0 = acc[0] * dd + bv.x, o1 = acc[1] * dd + bv.y;
  float o2 = acc[2] * dd + bv.z, o3 = acc[3] * dd + bv.w;

  if constexpr (sizeof(TOUT) == 2) {
    __half2 hp[2];
    hp[0] = __floats2half2_rn(o0, o1);
    hp[1] = __floats2half2_rn(o2, o3);
    *(float2*)&out[(long)d * C + c4] = *(float2*)hp;
  } else {
    *(float4*)&out[(long)d * C + c4] = make_float4(o0, o1, o2, o3);
  }
}

extern "C" void kernel_launch(void* const* d_in, const int* in_sizes, int n_in,
                              void* d_out, int out_size, void* d_ws, size_t ws_size,
                              hipStream_t stream) {
  const float* x  = (const float*)d_in[0];
  const void*  ep = d_in[1];
  const float* W1 = (const float*)d_in[2];
  const float* b1 = (const float*)d_in[3];
  const float* W2 = (const float*)d_in[4];
  const float* b2 = (const float*)d_in[5];
  float* out = (float*)d_out;
  const int E = in_sizes[1] / 2;

  // workspace layout — ALL int offsets multiples of 64 (256B-aligned; R13)
  float*  wsf    = (float*)d_ws;
  int*    wsi    = (int*)d_ws;
  int*    flag   = wsi;                        // [0]
  int*    bcur2  = wsi + 64;                   // 256*16 padded -> ends 4160
  float*  dinv   = wsf + 4224;                 // 100000 -> ends 104224
  int*    rowptr = wsi + 104256;               // 100001 -> ends 204257
  f16*    Wt1    = (f16*)(wsi + 204288);       // 16384 halves (8192 ints)
  f16*    Wt2    = (f16*)(wsi + 212480);       // 8192 halves (4096 ints)
  int*    csr    = wsi + 216576;               // 1600000 -> ends 1816576
  int*    pk     = wsi + 1816576;              // 2097152 -> ends 3913728
  f16*    hn1    = (f16*)(wsi + 3913728);      // 12.8M halves -> ends 10313728
  f16*    a1     = (f16*)(wsi + 10313728);     // 12.8M halves -> ends 16713728
  f16*    hn2    = hn1;                        // hn1 dead once a1 built

  const int SB = (E + 256 * EPB - 1) / (256 * EPB);  // 391
  const int GB = (NN + 127) / 128;                   // 782

  k_prep<<<25, 1024, 0, stream>>>((const unsigned*)ep, flag, bcur2, W1, W2, Wt1, Wt2);
  k_split<<<SB, 256, 0, stream>>>(ep, flag, E, bcur2, pk);
  k_build<<<NSB, 256, 0, stream>>>(pk, bcur2, rowptr, dinv, csr);

  // layer 1: hn1 = (x @ W1) * dinv ; a1 = dinv*(self + gather) + b1
  gemm_mfma<128, false, float><<<GB, 256, 0, stream>>>(x, Wt1, dinv, hn1);
  k_agg4<128, __half><<<(NN * 32 + 255) / 256, 256, 0, stream>>>(
      (const __half*)hn1, rowptr, csr, dinv, b1, (__half*)a1);

  // layer 2: hn2 = (relu(a1) @ W2) * dinv ; out = dinv*(self + gather) + b2
  gemm_mfma<64, true, f16><<<GB, 256, 0, stream>>>(a1, Wt2, dinv, hn2);
  k_agg4<64, float><<<(NN * 16 + 255) / 256, 256, 0, stream>>>(
      (const __half*)hn2, rowptr, csr, dinv, b2, out);
}